// Round 7
// baseline (112.584 us; speedup 1.0000x reference)
//
#include <hip/hip_runtime.h>
#include <math.h>

#define BATCH 4
#define LQ 2048
#define LK 2048
#define DIM 16
#define HEADS 2
#define DH 8
#define EPS 1e-5f

typedef float fvec4 __attribute__((ext_vector_type(4)));

// ---------------- Kernel A: fused LayerNorm + Linear for q,k,v ------------
__global__ __launch_bounds__(256) void ln_proj3_kernel(
    const float* __restrict__ xq, const float* __restrict__ xk,
    const float* __restrict__ xv,
    const float* __restrict__ gq, const float* __restrict__ bq_ln,
    const float* __restrict__ gk, const float* __restrict__ bk_ln,
    const float* __restrict__ gv, const float* __restrict__ bv_ln,
    const float* __restrict__ Wq, const float* __restrict__ bq,
    const float* __restrict__ Wk, const float* __restrict__ bk,
    const float* __restrict__ Wv, const float* __restrict__ bv,
    float* __restrict__ Qb, float* __restrict__ Kb, float* __restrict__ Vb,
    float* __restrict__ q0)
{
    const int gid = blockIdx.x * blockDim.x + threadIdx.x;
    const int which = gid >> 13;          // 0=q 1=k 2=v
    const int r     = gid & 8191;

    const float* x; const float* g; const float* bl;
    const float* W; const float* bb; float* outp; float scale;
    if (which == 0)      { x = xq; g = gq; bl = bq_ln; W = Wq; bb = bq; outp = Qb; scale = 0.35355339059327373f; }
    else if (which == 1) { x = xk; g = gk; bl = bk_ln; W = Wk; bb = bk; outp = Kb; scale = 1.0f; }
    else                 { x = xv; g = gv; bl = bv_ln; W = Wv; bb = bv; outp = Vb; scale = 1.0f; }

    float xv16[16];
    const float4* xp = (const float4*)(x + (size_t)r * 16);
#pragma unroll
    for (int i = 0; i < 4; ++i) {
        float4 t = xp[i];
        xv16[4*i+0] = t.x; xv16[4*i+1] = t.y; xv16[4*i+2] = t.z; xv16[4*i+3] = t.w;
    }
    float m = 0.f;
#pragma unroll
    for (int i = 0; i < 16; ++i) m += xv16[i];
    m *= (1.f / 16.f);
    float var = 0.f;
#pragma unroll
    for (int i = 0; i < 16; ++i) { float d = xv16[i] - m; var += d * d; }
    var *= (1.f / 16.f);
    float rs = rsqrtf(var + EPS);

    float xn[16];
#pragma unroll
    for (int i = 0; i < 16; ++i) xn[i] = (xv16[i] - m) * rs * g[i] + bl[i];

    if (which == 0) {
        float4* op = (float4*)(q0 + (size_t)r * 16);
#pragma unroll
        for (int i = 0; i < 4; ++i) {
            float4 t; t.x = xn[4*i+0]; t.y = xn[4*i+1]; t.z = xn[4*i+2]; t.w = xn[4*i+3];
            op[i] = t;
        }
    }

    const int b = r >> 11;
    const int l = r & 2047;
#pragma unroll
    for (int j = 0; j < 16; ++j) {
        float acc = bb[j];
#pragma unroll
        for (int i = 0; i < 16; ++i) acc += xn[i] * W[j * 16 + i];
        acc *= scale;
        int h = j >> 3, d = j & 7;
        outp[((((size_t)b * HEADS + h) * 2048) + l) * DH + d] = acc;
    }
}

// ---------------- Kernel B: wave = column-slice, K/V in registers ---------
// 512 threads = 8 waves; block covers 8 q-rows x 2048 cols of one (b,h).
// Wave w owns cols [w*256, w*256+256): K/V held in 64 VGPRs, loaded once.
// Main loop over 8 rows: w/mask prefetch, dot+exp, e -> LDS, 9-value
// butterfly (sum + 8 ctx partials) -> lane0 LDS. ONE barrier. Then wave w
// normalizes row w (e re-read, nontemporal store) and reduces its ctx.
__global__ __launch_bounds__(512, 2) void attn_kernel(
    const float* __restrict__ Q,    // (B,H,LQ,DH) pre-scaled by 1/sqrt(dh)
    const float* __restrict__ K,    // (B,H,LK,DH)
    const float* __restrict__ V,    // (B,H,LK,DH)
    const float* __restrict__ w,    // (B,H,LQ,LK)
    const float* __restrict__ mask, // (B,H,LQ,LK)
    float* __restrict__ attn_out,   // (B,H,LQ,LK)
    float* __restrict__ ctx)        // (B,LQ,H,DH) == (B,LQ,16)
{
    __shared__ fvec4 eS4[8][512];                    // e[row][col/4], 64 KB
    __shared__ __align__(16) float credS[8][8][8];   // [row][wave][d], 2 KB
    __shared__ __align__(16) float psumS[8][8];      // [row][wave], 256 B

    const int t    = threadIdx.x;
    const int lane = t & 63;
    const int wid  = t >> 6;                  // 0..7: col-slice in main, row in epilogue
    const int bh   = blockIdx.x >> 8;         // 8 panels x 256 blocks
    const int qbase= (blockIdx.x & 255) << 3;
    const int h    = bh & (HEADS - 1);
    const int b    = bh >> 1;
    const int c0   = (wid << 8) + (lane << 2);   // first of this lane's 4 cols

    // ---- K/V slice -> registers (no LDS, no barrier) ----
    const fvec4* Kg = (const fvec4*)(K + (size_t)bh * LK * DH);
    const fvec4* Vg = (const fvec4*)(V + (size_t)bh * LK * DH);
    fvec4 klo[4], khi[4], vlo[4], vhi[4];
#pragma unroll
    for (int j = 0; j < 4; ++j) {
        klo[j] = Kg[(size_t)(c0 + j) * 2 + 0];
        khi[j] = Kg[(size_t)(c0 + j) * 2 + 1];
        vlo[j] = Vg[(size_t)(c0 + j) * 2 + 0];
        vhi[j] = Vg[(size_t)(c0 + j) * 2 + 1];
    }

    const float* wrow = w    + (((size_t)bh << 11) + qbase) * LK + c0;
    const float* mrow = mask + (((size_t)bh << 11) + qbase) * LK + c0;
    const fvec4* Qp   = (const fvec4*)(Q + (((size_t)bh << 11) + qbase) * DH);

    fvec4 wv = __builtin_nontemporal_load((const fvec4*)wrow);
    fvec4 mv = __builtin_nontemporal_load((const fvec4*)mrow);
    fvec4 qlo = Qp[0], qhi = Qp[1];          // wave-uniform -> scalar loads

#pragma unroll
    for (int r = 0; r < 8; ++r) {
        fvec4 wn, mn, qnlo, qnhi;
        if (r < 7) {
            wn = __builtin_nontemporal_load((const fvec4*)(wrow + (size_t)(r + 1) * LK));
            mn = __builtin_nontemporal_load((const fvec4*)(mrow + (size_t)(r + 1) * LK));
            qnlo = Qp[2 * (r + 1)]; qnhi = Qp[2 * (r + 1) + 1];
        }
        // scores for 4 cols (softmax shift-invariant; |s|<~10, fp32 exp safe)
        fvec4 s = wv + mv;
#pragma unroll
        for (int j = 0; j < 4; ++j) {
            s[j] += qlo.x * klo[j].x + qlo.y * klo[j].y + qlo.z * klo[j].z + qlo.w * klo[j].w
                  + qhi.x * khi[j].x + qhi.y * khi[j].y + qhi.z * khi[j].z + qhi.w * khi[j].w;
        }
        fvec4 e;
        e.x = __expf(s.x); e.y = __expf(s.y); e.z = __expf(s.z); e.w = __expf(s.w);
        eS4[r][(wid << 6) + lane] = e;       // contiguous b128 per wave
        float ps = e.x + e.y + e.z + e.w;
        fvec4 cl = e.x * vlo[0] + e.y * vlo[1] + e.z * vlo[2] + e.w * vlo[3];
        fvec4 ch = e.x * vhi[0] + e.y * vhi[1] + e.z * vhi[2] + e.w * vhi[3];
        // 9-value wave butterfly
#pragma unroll
        for (int off = 32; off > 0; off >>= 1) {
            ps   += __shfl_xor(ps, off);
            cl.x += __shfl_xor(cl.x, off); cl.y += __shfl_xor(cl.y, off);
            cl.z += __shfl_xor(cl.z, off); cl.w += __shfl_xor(cl.w, off);
            ch.x += __shfl_xor(ch.x, off); ch.y += __shfl_xor(ch.y, off);
            ch.z += __shfl_xor(ch.z, off); ch.w += __shfl_xor(ch.w, off);
        }
        if (lane == 0) {
            psumS[r][wid] = ps;
            *(fvec4*)&credS[r][wid][0] = cl;
            *(fvec4*)&credS[r][wid][4] = ch;
        }
        wv = wn; mv = mn; qlo = qnlo; qhi = qnhi;
    }

    __syncthreads();   // the ONLY barrier

    // ---- epilogue: wave wid owns row wid ----
    const int q = qbase + wid;
    const size_t rowid = ((size_t)bh << 11) + q;
    float rsum = 0.f;
#pragma unroll
    for (int j = 0; j < 8; ++j) rsum += psumS[wid][j];
    const float inv = 1.f / rsum;

    float* arow = attn_out + rowid * LK;
#pragma unroll
    for (int j = 0; j < 8; ++j) {
        const int ci = (j << 6) + lane;      // col/4
        fvec4 ev = eS4[wid][ci] * inv;
        __builtin_nontemporal_store(ev, (fvec4*)(arow + (ci << 2)));
    }

    if (lane < 8) {
        float acc = 0.f;
#pragma unroll
        for (int j = 0; j < 8; ++j) acc += credS[wid][j][lane];
        ctx[((((size_t)b * LQ + q) * HEADS) + h) * DH + lane] = acc * inv;
    }
}

// ---------------- Kernel C: output projection + residual ------------------
__global__ __launch_bounds__(256) void out_kernel(
    const float* __restrict__ ctx,  // (B,LQ,16)
    const float* __restrict__ Wo,   // (16,16)
    const float* __restrict__ bo,   // (16,)
    const float* __restrict__ q0,   // (B,LQ,16)
    float* __restrict__ out, int n)
{
    int gid = blockIdx.x * blockDim.x + threadIdx.x;
    if (gid >= n) return;
    int row = gid >> 4, j = gid & 15;
    const float* c = ctx + (size_t)row * 16;
    float acc = bo[j];
#pragma unroll
    for (int i = 0; i < 16; ++i) acc += c[i] * Wo[j * 16 + i];
    out[gid] = acc + q0[gid];
}

extern "C" void kernel_launch(void* const* d_in, const int* in_sizes, int n_in,
                              void* d_out, int out_size, void* d_ws, size_t ws_size,
                              hipStream_t stream) {
    const float* query = (const float*)d_in[0];
    const float* key_  = (const float*)d_in[1];
    const float* value = (const float*)d_in[2];
    const float* w     = (const float*)d_in[3];
    const float* mask  = (const float*)d_in[4];
    const float* ln_qg = (const float*)d_in[5];
    const float* ln_qb = (const float*)d_in[6];
    const float* ln_kg = (const float*)d_in[7];
    const float* ln_kb = (const float*)d_in[8];
    const float* ln_vg = (const float*)d_in[9];
    const float* ln_vb = (const float*)d_in[10];
    const float* Wq = (const float*)d_in[11];
    const float* bq = (const float*)d_in[12];
    const float* Wk = (const float*)d_in[13];
    const float* bk = (const float*)d_in[14];
    const float* Wv = (const float*)d_in[15];
    const float* bv = (const float*)d_in[16];
    const float* Wo = (const float*)d_in[17];
    const float* bo = (const float*)d_in[18];

    float* out  = (float*)d_out;                       // (B,LQ,16) first
    float* attn = out + (size_t)BATCH * LQ * DIM;      // then (B,H,LQ,LK)

    const size_t NE = (size_t)BATCH * LQ * DIM;        // 131072
    float* ws  = (float*)d_ws;
    float* Qb  = ws;            // (B,H,LQ,DH)
    float* Kb  = Qb + NE;       // (B,H,LK,DH)
    float* Vb  = Kb + NE;       // (B,H,LK,DH)
    float* q0  = Vb + NE;       // (B,LQ,16)
    float* ctx = q0 + NE;       // (B,LQ,16)

    ln_proj3_kernel<<<(3 * 8192) / 256, 256, 0, stream>>>(
        query, key_, value,
        ln_qg, ln_qb, ln_kg, ln_kb, ln_vg, ln_vb,
        Wq, bq, Wk, bk, Wv, bv,
        Qb, Kb, Vb, q0);

    // 2048 blocks: 8 bh panels x 256 blocks, 8 q-rows per block
    attn_kernel<<<BATCH * HEADS * LQ / 8, 512, 0, stream>>>(
        Qb, Kb, Vb, w, mask, attn, ctx);

    out_kernel<<<((int)NE + 255) / 256, 256, 0, stream>>>(
        ctx, Wo, bo, q0, out, (int)NE);
}